// Round 1
// baseline (27590.808 us; speedup 1.0000x reference)
//
#include <hip/hip_runtime.h>
#include <math.h>

// Problem constants
constexpr int Bc = 16;     // batch
constexpr int Tc = 64;     // tokens == prefixes
constexpr int INc = 128;
constexpr int Dc = 512;
constexpr int Hc = 8;
constexpr int HDc = 64;
constexpr int Fc = 2048;
constexpr int Lc = 4;
constexpr float SCALEc = 0.125f;  // 1/sqrt(64)

// ---------------------------------------------------------------------------
// Generic fp32 GEMM: C[M,N] = op(A[M,K] @ W[K,N] + bias[N]), op = relu or id.
// 128x64 tile, BK=16, 256 threads, 8x4 micro-tile (rows ty+16*i, cols tx*4+j).
// Requires: M % 128 == 0, N % 64 == 0, K % 16 == 0.
// ---------------------------------------------------------------------------
template<bool RELU>
__global__ __launch_bounds__(256) void gemm_kernel(
    const float* __restrict__ A, const float* __restrict__ W,
    const float* __restrict__ bias, float* __restrict__ C,
    int M, int K, int N)
{
  __shared__ float As[128][17];   // +1 pad: conflict-free column reads
  __shared__ float Ws[16][64];

  const int tid = threadIdx.x;
  const int tx = tid & 15;
  const int ty = tid >> 4;
  const int row0 = blockIdx.y * 128;
  const int col0 = blockIdx.x * 64;

  float acc[8][4];
#pragma unroll
  for (int i = 0; i < 8; ++i)
#pragma unroll
    for (int j = 0; j < 4; ++j) acc[i][j] = 0.f;

  const int ar = tid >> 1;          // 0..127 (A row within tile)
  const int ak = (tid & 1) * 8;     // 0 or 8 (A k-offset)
  const int wr = tid >> 4;          // 0..15  (W row within tile)
  const int wc = (tid & 15) * 4;    // 0..60  (W col offset)

  for (int k0 = 0; k0 < K; k0 += 16) {
    const float* ap = A + (size_t)(row0 + ar) * K + k0 + ak;
    float4 a0 = *(const float4*)ap;
    float4 a1 = *(const float4*)(ap + 4);
    As[ar][ak + 0] = a0.x; As[ar][ak + 1] = a0.y;
    As[ar][ak + 2] = a0.z; As[ar][ak + 3] = a0.w;
    As[ar][ak + 4] = a1.x; As[ar][ak + 5] = a1.y;
    As[ar][ak + 6] = a1.z; As[ar][ak + 7] = a1.w;

    const float4 wv = *(const float4*)(W + (size_t)(k0 + wr) * N + col0 + wc);
    *(float4*)&Ws[wr][wc] = wv;

    __syncthreads();
#pragma unroll
    for (int kk = 0; kk < 16; ++kk) {
      const float4 w4 = *(const float4*)&Ws[kk][tx * 4];
#pragma unroll
      for (int i = 0; i < 8; ++i) {
        const float av = As[ty + 16 * i][kk];
        acc[i][0] += av * w4.x;
        acc[i][1] += av * w4.y;
        acc[i][2] += av * w4.z;
        acc[i][3] += av * w4.w;
      }
    }
    __syncthreads();
  }

#pragma unroll
  for (int i = 0; i < 8; ++i) {
    const int r = row0 + ty + 16 * i;
    const int c = col0 + tx * 4;
    float4 v;
    v.x = acc[i][0] + bias[c + 0];
    v.y = acc[i][1] + bias[c + 1];
    v.z = acc[i][2] + bias[c + 2];
    v.w = acc[i][3] + bias[c + 3];
    if (RELU) {
      v.x = fmaxf(v.x, 0.f); v.y = fmaxf(v.y, 0.f);
      v.z = fmaxf(v.z, 0.f); v.w = fmaxf(v.w, 0.f);
    }
    *(float4*)&C[(size_t)r * N + c] = v;
  }
}

// ---------------------------------------------------------------------------
// Broadcast h0 [B*T, D] to h [PC*B*T, D] (prefix copies). float4 granularity.
// ---------------------------------------------------------------------------
__global__ void bcast_kernel(const float4* __restrict__ h0, float4* __restrict__ h, int n)
{
  int i = blockIdx.x * blockDim.x + threadIdx.x;
  if (i < n) h[i] = h0[i & (Bc * Tc * Dc / 4 - 1)];  // 131072 float4 per copy (pow2)
}

// ---------------------------------------------------------------------------
// Attention for one (prefix, batch, head). 64 threads; thread = query row.
// qkv rows are [q(512) | k(512) | v(512)]. Keys masked to t_k <= p.
// Scores/probs kept in the (reused) Q LDS tile to avoid scratch spills.
// ---------------------------------------------------------------------------
__global__ __launch_bounds__(64) void attn_kernel(
    const float* __restrict__ qkv, float* __restrict__ attno, int p0)
{
  const int hh = blockIdx.x;   // head
  const int b  = blockIdx.y;
  const int pl = blockIdx.z;   // local prefix
  const int p  = p0 + pl;      // global prefix
  const int tid = threadIdx.x;

  __shared__ float Qs[64][65];
  __shared__ float Ks[64][65];
  __shared__ float Vs[64][65];

  const size_t base = (size_t)(pl * Bc + b) * Tc * (3 * Dc);
  const int hoff = hh * HDc;

  for (int r = 0; r < 64; ++r) {
    const float* src = qkv + base + (size_t)r * (3 * Dc) + hoff;
    Qs[r][tid] = src[tid];
    Ks[r][tid] = src[512 + tid];
    Vs[r][tid] = src[1024 + tid];
  }
  __syncthreads();

  // cache this thread's query row in registers (static indices only)
  float qv[64];
#pragma unroll
  for (int d = 0; d < 64; ++d) qv[d] = Qs[tid][d];

  // scores -> reuse own Qs row (only thread tid touches row tid)
  float m = -1e30f;
  for (int k = 0; k < 64; ++k) {
    float dot = 0.f;
#pragma unroll
    for (int d = 0; d < 64; ++d) dot += qv[d] * Ks[k][d];
    dot *= SCALEc;
    Qs[tid][k] = dot;
    if (k <= p) m = fmaxf(m, dot);
  }
  float sum = 0.f;
  for (int k = 0; k < 64; ++k) {
    float e = (k <= p) ? expf(Qs[tid][k] - m) : 0.f;
    Qs[tid][k] = e;
    sum += e;
  }
  const float inv = 1.f / sum;

  float* dst = attno + ((size_t)((pl * Bc + b) * Tc + tid)) * Dc + hoff;
  for (int d = 0; d < 64; ++d) {
    float o = 0.f;
    for (int k = 0; k < 64; ++k) o += Qs[tid][k] * Vs[k][d];
    dst[d] = o * inv;
  }
}

// ---------------------------------------------------------------------------
// h[row] = LN(h[row] + tmp[row]) * g + b   (one 64-thread wave per row, D=512)
// ---------------------------------------------------------------------------
__device__ inline float wave_sum(float v) {
#pragma unroll
  for (int off = 32; off; off >>= 1) v += __shfl_xor(v, off);
  return v;
}

__global__ __launch_bounds__(64) void res_ln_kernel(
    float* __restrict__ h, const float* __restrict__ tmp,
    const float* __restrict__ g, const float* __restrict__ bt)
{
  const size_t row = blockIdx.x;
  const int t = threadIdx.x;
  float v[8];
  float s = 0.f;
#pragma unroll
  for (int i = 0; i < 8; ++i) {
    v[i] = h[row * Dc + i * 64 + t] + tmp[row * Dc + i * 64 + t];
    s += v[i];
  }
  s = wave_sum(s);
  const float mean = s * (1.f / 512.f);
  float vs = 0.f;
#pragma unroll
  for (int i = 0; i < 8; ++i) { const float d = v[i] - mean; vs += d * d; }
  vs = wave_sum(vs);
  const float rstd = rsqrtf(vs * (1.f / 512.f) + 1e-5f);
#pragma unroll
  for (int i = 0; i < 8; ++i)
    h[row * Dc + i * 64 + t] = (v[i] - mean) * rstd * g[i * 64 + t] + bt[i * 64 + t];
}

// ---------------------------------------------------------------------------
// y[(b,p),:] = h[((pl*B+b)*T + p),:]   (token p of prefix p)
// ---------------------------------------------------------------------------
__global__ void gather_kernel(const float* __restrict__ h, float* __restrict__ y, int p0)
{
  const int pl = blockIdx.x >> 4;
  const int b  = blockIdx.x & 15;
  const int p  = p0 + pl;
  const float* src = h + ((size_t)((pl * Bc + b) * Tc + p)) * Dc;
  float* dst = y + ((size_t)(b * Tc + p)) * Dc;
  dst[threadIdx.x] = src[threadIdx.x];
}

// ---------------------------------------------------------------------------
// Classifier + log_softmax. One 256-thread block per (b,t) row.
// ---------------------------------------------------------------------------
__global__ __launch_bounds__(256) void cls_kernel(
    const float* __restrict__ y, const float* __restrict__ w1, const float* __restrict__ b1,
    const float* __restrict__ w2, const float* __restrict__ b2, float* __restrict__ out)
{
  const int row = blockIdx.x;
  const int j = threadIdx.x;
  __shared__ float ys[512];
  ys[j]       = y[(size_t)row * Dc + j];
  ys[j + 256] = y[(size_t)row * Dc + 256 + j];
  __syncthreads();

  float acc = b1[j];
  for (int d = 0; d < 512; ++d) acc += ys[d] * w1[(size_t)d * 256 + j];
  acc = fmaxf(acc, 0.f);

  float c0 = acc * w2[j * 2 + 0];
  float c1 = acc * w2[j * 2 + 1];
  c0 = wave_sum(c0);
  c1 = wave_sum(c1);

  __shared__ float r0[4], r1[4];
  const int w = j >> 6, lane = j & 63;
  if (lane == 0) { r0[w] = c0; r1[w] = c1; }
  __syncthreads();
  if (j == 0) {
    const float z0 = r0[0] + r0[1] + r0[2] + r0[3] + b2[0];
    const float z1 = r1[0] + r1[1] + r1[2] + r1[3] + b2[1];
    const float mz = fmaxf(z0, z1);
    const float lse = mz + logf(expf(z0 - mz) + expf(z1 - mz));
    out[row * 2 + 0] = z0 - lse;
    out[row * 2 + 1] = z1 - lse;
  }
}

// ---------------------------------------------------------------------------
extern "C" void kernel_launch(void* const* d_in, const int* in_sizes, int n_in,
                              void* d_out, int out_size, void* d_ws, size_t ws_size,
                              hipStream_t stream)
{
  if (n_in < 19) return;
  const float* x      = (const float*)d_in[0];
  const float* fc_w   = (const float*)d_in[1];
  const float* fc_b   = (const float*)d_in[2];
  const float* w_qkv  = (const float*)d_in[3];
  const float* b_qkv  = (const float*)d_in[4];
  const float* w_o    = (const float*)d_in[5];
  const float* b_o    = (const float*)d_in[6];
  const float* ln1_g  = (const float*)d_in[7];
  const float* ln1_b  = (const float*)d_in[8];
  const float* w_ff1  = (const float*)d_in[9];
  const float* b_ff1  = (const float*)d_in[10];
  const float* w_ff2  = (const float*)d_in[11];
  const float* b_ff2  = (const float*)d_in[12];
  const float* ln2_g  = (const float*)d_in[13];
  const float* ln2_b  = (const float*)d_in[14];
  const float* cls_w1 = (const float*)d_in[15];
  const float* cls_b1 = (const float*)d_in[16];
  const float* cls_w2 = (const float*)d_in[17];
  const float* cls_b2 = (const float*)d_in[18];
  float* out = (float*)d_out;

  // choose prefix-chunk size PC (deterministic: depends only on ws_size)
  // per-row floats: h(512) + qkv(1536) + attno(512) + ff(2048) = 4608
  int PC = 64;
  while (PC > 1) {
    size_t need = 4ull * (1048576ull + (size_t)PC * 1024ull * 4608ull);
    if (need <= ws_size) break;
    PC >>= 1;
  }
  {
    size_t need = 4ull * (1048576ull + (size_t)PC * 1024ull * 4608ull);
    if (need > ws_size) return;  // workspace too small to run at all
  }
  const size_t R = (size_t)PC * Bc * Tc;   // rows per chunk

  float* ws    = (float*)d_ws;
  float* h0    = ws;                 // [B*T, D]     = 524288
  float* yb    = h0 + (size_t)Bc * Tc * Dc;   // [B*T, D]
  float* h     = yb + (size_t)Bc * Tc * Dc;   // [R, D]
  float* qkvb  = h + R * Dc;                  // [R, 3D] (also reused as tmp [R,D])
  float* attno = qkvb + R * 3 * Dc;           // [R, D]
  float* ffb   = attno + R * Dc;              // [R, F]

  // h0 = relu(x @ fc_w + fc_b)   M=1024, K=128, N=512
  gemm_kernel<true><<<dim3(Dc / 64, (Bc * Tc) / 128), 256, 0, stream>>>(
      x, fc_w, fc_b, h0, Bc * Tc, INc, Dc);

  for (int p0 = 0; p0 < Tc; p0 += PC) {
    const int n4 = (int)(R * Dc / 4);
    bcast_kernel<<<(n4 + 255) / 256, 256, 0, stream>>>(
        (const float4*)h0, (float4*)h, n4);

    for (int l = 0; l < Lc; ++l) {
      const float* Wqkv = w_qkv + (size_t)l * Dc * 3 * Dc;
      const float* bqkv = b_qkv + (size_t)l * 3 * Dc;
      const float* Wo   = w_o   + (size_t)l * Dc * Dc;
      const float* bo   = b_o   + (size_t)l * Dc;
      const float* Wf1  = w_ff1 + (size_t)l * Dc * Fc;
      const float* bf1  = b_ff1 + (size_t)l * Fc;
      const float* Wf2  = w_ff2 + (size_t)l * Fc * Dc;
      const float* bf2  = b_ff2 + (size_t)l * Dc;

      // qkv = h @ Wqkv + b
      gemm_kernel<false><<<dim3(3 * Dc / 64, (int)(R / 128)), 256, 0, stream>>>(
          h, Wqkv, bqkv, qkvb, (int)R, Dc, 3 * Dc);
      // attention (per prefix/batch/head), keys masked to <= p
      attn_kernel<<<dim3(Hc, Bc, PC), 64, 0, stream>>>(qkvb, attno, p0);
      // tmp = attno @ Wo + b_o   (tmp aliases qkvb, [R,512])
      gemm_kernel<false><<<dim3(Dc / 64, (int)(R / 128)), 256, 0, stream>>>(
          attno, Wo, bo, qkvb, (int)R, Dc, Dc);
      // h = LN(h + tmp)
      res_ln_kernel<<<(int)R, 64, 0, stream>>>(h, qkvb, ln1_g + l * Dc, ln1_b + l * Dc);
      // ff = relu(h @ Wf1 + b)
      gemm_kernel<true><<<dim3(Fc / 64, (int)(R / 128)), 256, 0, stream>>>(
          h, Wf1, bf1, ffb, (int)R, Dc, Fc);
      // tmp = ff @ Wf2 + b  (tmp aliases qkvb)
      gemm_kernel<false><<<dim3(Dc / 64, (int)(R / 128)), 256, 0, stream>>>(
          ffb, Wf2, bf2, qkvb, (int)R, Fc, Dc);
      // h = LN(h + tmp)
      res_ln_kernel<<<(int)R, 64, 0, stream>>>(h, qkvb, ln2_g + l * Dc, ln2_b + l * Dc);
    }
    gather_kernel<<<PC * Bc, Dc, 0, stream>>>(h, yb, p0);
  }

  cls_kernel<<<Bc * Tc, 256, 0, stream>>>(yb, cls_w1, cls_b1, cls_w2, cls_b2, out);
}

// Round 2
// 5220.635 us; speedup vs baseline: 5.2850x; 5.2850x over previous
//
#include <hip/hip_runtime.h>
#include <math.h>

using u16 = unsigned short;
using u32 = unsigned int;

constexpr int Bc = 16;     // batch
constexpr int Tc = 64;     // tokens == prefixes
constexpr int INc = 128;
constexpr int Dc = 512;
constexpr int Hc = 8;
constexpr int Fc = 2048;
constexpr int Lc = 4;
constexpr float SCALEc = 0.125f;  // 1/sqrt(64)

typedef __attribute__((ext_vector_type(8))) short bf16x8;
typedef __attribute__((ext_vector_type(4))) float f32x4;

__device__ __forceinline__ float bf2f(u16 u) {
  union { u32 i; float f; } c; c.i = (u32)u << 16; return c.f;
}
__device__ __forceinline__ u16 f2bf(float f) {
  union { float f; u32 u; } c{f};
  u32 r = (c.u + 0x7fffu + ((c.u >> 16) & 1u)) >> 16;
  return (u16)r;
}

// ---------------------------------------------------------------------------
// fp32 GEMM (kept only for the small fc layer: M=1024,K=128,N=512)
// ---------------------------------------------------------------------------
template<bool RELU>
__global__ __launch_bounds__(256) void gemm_kernel(
    const float* __restrict__ A, const float* __restrict__ W,
    const float* __restrict__ bias, float* __restrict__ C,
    int M, int K, int N)
{
  __shared__ float As[128][17];
  __shared__ float Ws[16][64];
  const int tid = threadIdx.x;
  const int tx = tid & 15, ty = tid >> 4;
  const int row0 = blockIdx.y * 128, col0 = blockIdx.x * 64;
  float acc[8][4];
#pragma unroll
  for (int i = 0; i < 8; ++i)
#pragma unroll
    for (int j = 0; j < 4; ++j) acc[i][j] = 0.f;
  const int ar = tid >> 1, ak = (tid & 1) * 8;
  const int wr = tid >> 4, wc = (tid & 15) * 4;
  for (int k0 = 0; k0 < K; k0 += 16) {
    const float* ap = A + (size_t)(row0 + ar) * K + k0 + ak;
    float4 a0 = *(const float4*)ap;
    float4 a1 = *(const float4*)(ap + 4);
    As[ar][ak+0]=a0.x; As[ar][ak+1]=a0.y; As[ar][ak+2]=a0.z; As[ar][ak+3]=a0.w;
    As[ar][ak+4]=a1.x; As[ar][ak+5]=a1.y; As[ar][ak+6]=a1.z; As[ar][ak+7]=a1.w;
    *(float4*)&Ws[wr][wc] = *(const float4*)(W + (size_t)(k0 + wr) * N + col0 + wc);
    __syncthreads();
#pragma unroll
    for (int kk = 0; kk < 16; ++kk) {
      const float4 w4 = *(const float4*)&Ws[kk][tx * 4];
#pragma unroll
      for (int i = 0; i < 8; ++i) {
        const float av = As[ty + 16 * i][kk];
        acc[i][0] += av * w4.x; acc[i][1] += av * w4.y;
        acc[i][2] += av * w4.z; acc[i][3] += av * w4.w;
      }
    }
    __syncthreads();
  }
#pragma unroll
  for (int i = 0; i < 8; ++i) {
    const int r = row0 + ty + 16 * i, c = col0 + tx * 4;
    float4 v;
    v.x = acc[i][0] + bias[c+0]; v.y = acc[i][1] + bias[c+1];
    v.z = acc[i][2] + bias[c+2]; v.w = acc[i][3] + bias[c+3];
    if (RELU) { v.x=fmaxf(v.x,0.f); v.y=fmaxf(v.y,0.f); v.z=fmaxf(v.z,0.f); v.w=fmaxf(v.w,0.f); }
    *(float4*)&C[(size_t)r * N + c] = v;
  }
}

// ---------------------------------------------------------------------------
// Weight convert+transpose: src fp32 [K][N] -> dst bf16 [N][K]
// ---------------------------------------------------------------------------
__global__ __launch_bounds__(256) void transpose_conv(
    const float* __restrict__ src, u16* __restrict__ dst, int K, int N)
{
  __shared__ float t[32][33];
  const int bx = blockIdx.x * 32;   // n
  const int by = blockIdx.y * 32;   // k
  const int x = threadIdx.x, y = threadIdx.y;  // 32 x 8
#pragma unroll
  for (int i = 0; i < 32; i += 8) t[y + i][x] = src[(size_t)(by + y + i) * N + bx + x];
  __syncthreads();
#pragma unroll
  for (int i = 0; i < 32; i += 8)
    dst[(size_t)(bx + y + i) * K + by + x] = f2bf(t[x][y + i]);
}

// ---------------------------------------------------------------------------
// bf16 MFMA GEMM: C[M,N] = op(A[M,K] @ Wt[N,K]^T + bias), 128x128 tile, BK=64.
// A, Wt bf16; C fp32 or bf16. M%128==0, N%128==0, K%64==0.
// LDS tiles [128 rows][64 k] with 16B-granule XOR swizzle (slot ^= row&7).
// ---------------------------------------------------------------------------
__device__ __forceinline__ void stage_tile(const u16* __restrict__ src, int ldk, u16* lds)
{
  const int tid = threadIdx.x;
#pragma unroll
  for (int q = 0; q < 4; ++q) {
    const int p16 = tid + (q << 8);      // 16B granule 0..1023
    const int row = p16 >> 3;            // 8 granules per 128B row
    const int s   = p16 & 7;
    const int k16 = s ^ (row & 7);       // pre-swizzled SOURCE, linear dest
    const u16* g = src + (size_t)row * ldk + (k16 << 3);
    __builtin_amdgcn_global_load_lds(
        (const __attribute__((address_space(1))) void*)g,
        (__attribute__((address_space(3))) void*)(lds + (p16 << 3)),
        16, 0, 0);
  }
}

template<bool RELU, bool OUT_BF16>
__global__ __launch_bounds__(256) void gemm_mfma(
    const u16* __restrict__ A,    // [M][K] bf16
    const u16* __restrict__ Wt,   // [N][K] bf16
    const float* __restrict__ bias,
    void* __restrict__ Cout,
    int M, int K, int N)
{
  __shared__ u16 As[2][128 * 64];
  __shared__ u16 Bs[2][128 * 64];

  const int tid  = threadIdx.x;
  const int lane = tid & 63;
  const int wave = tid >> 6;
  const int wr = wave >> 1;       // 0..1  (row half)
  const int wc = wave & 1;        // 0..1  (col half)
  const int row0 = blockIdx.y * 128;
  const int col0 = blockIdx.x * 128;

  f32x4 acc[4][4];
#pragma unroll
  for (int i = 0; i < 4; ++i)
#pragma unroll
    for (int j = 0; j < 4; ++j) acc[i][j] = f32x4{0.f, 0.f, 0.f, 0.f};

  const int nk = K >> 6;
  stage_tile(A  + (size_t)row0 * K, K, &As[0][0]);
  stage_tile(Wt + (size_t)col0 * K, K, &Bs[0][0]);
  asm volatile("s_waitcnt vmcnt(0)" ::: "memory");
  __syncthreads();

  const int arow = wr * 64 + (lane & 15);   // A row base (within tile)
  const int brow = wc * 64 + (lane & 15);   // B row base (= C col)
  const int kq   = lane >> 4;               // 0..3

  for (int t = 0; t < nk; ++t) {
    const int cur = t & 1;
    if (t + 1 < nk) {
      const int k0 = (t + 1) << 6;
      stage_tile(A  + (size_t)row0 * K + k0, K, &As[cur ^ 1][0]);
      stage_tile(Wt + (size_t)col0 * K + k0, K, &Bs[cur ^ 1][0]);
    }
    const u16* Ab = &As[cur][0];
    const u16* Bb = &Bs[cur][0];
#pragma unroll
    for (int kk = 0; kk < 2; ++kk) {
      bf16x8 af[4], bfr[4];
      const int c = kk * 4 + kq;
#pragma unroll
      for (int i = 0; i < 4; ++i) {
        const int ra = arow + i * 16;
        af[i]  = *reinterpret_cast<const bf16x8*>(Ab + ra * 64 + ((c ^ (ra & 7)) << 3));
        const int rb = brow + i * 16;
        bfr[i] = *reinterpret_cast<const bf16x8*>(Bb + rb * 64 + ((c ^ (rb & 7)) << 3));
      }
#pragma unroll
      for (int mi = 0; mi < 4; ++mi)
#pragma unroll
        for (int ni = 0; ni < 4; ++ni)
          acc[mi][ni] = __builtin_amdgcn_mfma_f32_16x16x32_bf16(af[mi], bfr[ni], acc[mi][ni], 0, 0, 0);
    }
    asm volatile("s_waitcnt vmcnt(0)" ::: "memory");
    __syncthreads();
  }

  // epilogue: C/D layout col=lane&15, row=(lane>>4)*4+j   [m89-verified]
  const int r0 = row0 + wr * 64 + ((lane >> 4) << 2);
  const int c0 = col0 + wc * 64 + (lane & 15);
#pragma unroll
  for (int mi = 0; mi < 4; ++mi)
#pragma unroll
    for (int ni = 0; ni < 4; ++ni) {
      const int col = c0 + ni * 16;
      const float bsv = bias[col];
#pragma unroll
      for (int j = 0; j < 4; ++j) {
        const int row = r0 + mi * 16 + j;
        float o = acc[mi][ni][j] + bsv;
        if (RELU) o = fmaxf(o, 0.f);
        if (OUT_BF16) ((u16*)Cout)[(size_t)row * N + col] = f2bf(o);
        else          ((float*)Cout)[(size_t)row * N + col] = o;
      }
    }
}

// ---------------------------------------------------------------------------
// Broadcast h0 fp32 -> h fp32 + hb bf16 (prefix copies)
// ---------------------------------------------------------------------------
__global__ void bcast_kernel(const float4* __restrict__ h0, float4* __restrict__ h,
                             uint2* __restrict__ hb, int n4)
{
  const int i = blockIdx.x * blockDim.x + threadIdx.x;
  if (i >= n4) return;
  const float4 v = h0[i & (Bc * Tc * Dc / 4 - 1)];
  h[i] = v;
  uint2 pk;
  pk.x = (u32)f2bf(v.x) | ((u32)f2bf(v.y) << 16);
  pk.y = (u32)f2bf(v.z) | ((u32)f2bf(v.w) << 16);
  hb[i] = pk;
}

// ---------------------------------------------------------------------------
// Attention, bf16 in/out. One 64-thread block per (prefix, batch, head).
// Only keys k <= p are computed (masked keys skipped entirely).
// ---------------------------------------------------------------------------
__global__ __launch_bounds__(64) void attn_kernel(
    const u16* __restrict__ qkv, u16* __restrict__ attno, int p0)
{
  const int hh = blockIdx.x, b = blockIdx.y, pl = blockIdx.z;
  const int p = p0 + pl;
  const int tid = threadIdx.x;
  __shared__ u16 Ks[64][64];
  __shared__ u16 Vs[64][64];
  __shared__ float Sc[64][65];
  const size_t base = (size_t)(pl * Bc + b) * Tc * 1536 + hh * 64;

  for (int r = 0; r < 64; ++r) {
    const u16* src = qkv + base + (size_t)r * 1536;
    if (tid < 32)
      *reinterpret_cast<u32*>(&Ks[r][2 * tid]) = *reinterpret_cast<const u32*>(src + 512 + 2 * tid);
    else
      *reinterpret_cast<u32*>(&Vs[r][2 * (tid - 32)]) = *reinterpret_cast<const u32*>(src + 1024 + 2 * (tid - 32));
  }
  float qv[64];
  {
    const u16* qp = qkv + base + (size_t)tid * 1536;
#pragma unroll
    for (int c8 = 0; c8 < 8; ++c8) {
      const bf16x8 q8 = *reinterpret_cast<const bf16x8*>(qp + c8 * 8);
#pragma unroll
      for (int i = 0; i < 8; ++i) qv[c8 * 8 + i] = bf2f((u16)q8[i]);
    }
  }
  __syncthreads();

  float m = -1e30f;
  for (int k = 0; k <= p; ++k) {
    float dot = 0.f;
#pragma unroll
    for (int c8 = 0; c8 < 8; ++c8) {
      const bf16x8 k8 = *reinterpret_cast<const bf16x8*>(&Ks[k][c8 * 8]);
#pragma unroll
      for (int i = 0; i < 8; ++i) dot += qv[c8 * 8 + i] * bf2f((u16)k8[i]);
    }
    dot *= SCALEc;
    Sc[tid][k] = dot;
    m = fmaxf(m, dot);
  }
  float sum = 0.f;
  for (int k = 0; k <= p; ++k) {
    const float e = __expf(Sc[tid][k] - m);
    Sc[tid][k] = e;
    sum += e;
  }
  const float inv = 1.f / sum;

  u16* dst = attno + ((size_t)((pl * Bc + b) * Tc + tid)) * Dc + hh * 64;
#pragma unroll 2
  for (int d = 0; d < 64; ++d) {
    float o = 0.f;
    for (int k = 0; k <= p; ++k) o += Sc[tid][k] * bf2f(Vs[k][d]);
    dst[d] = f2bf(o * inv);
  }
}

// ---------------------------------------------------------------------------
// h = LN(h + tmp); also writes hb (bf16 copy). One wave per row, D=512.
// ---------------------------------------------------------------------------
__device__ inline float wave_sum(float v) {
#pragma unroll
  for (int off = 32; off; off >>= 1) v += __shfl_xor(v, off);
  return v;
}

__global__ __launch_bounds__(64) void res_ln_kernel(
    float* __restrict__ h, u16* __restrict__ hb, const float* __restrict__ tmp,
    const float* __restrict__ g, const float* __restrict__ bt)
{
  const size_t row = blockIdx.x;
  const int t = threadIdx.x;
  float v[8];
  float s = 0.f;
#pragma unroll
  for (int i = 0; i < 8; ++i) {
    v[i] = h[row * Dc + i * 64 + t] + tmp[row * Dc + i * 64 + t];
    s += v[i];
  }
  s = wave_sum(s);
  const float mean = s * (1.f / 512.f);
  float vs = 0.f;
#pragma unroll
  for (int i = 0; i < 8; ++i) { const float d = v[i] - mean; vs += d * d; }
  vs = wave_sum(vs);
  const float rstd = rsqrtf(vs * (1.f / 512.f) + 1e-5f);
#pragma unroll
  for (int i = 0; i < 8; ++i) {
    const float o = (v[i] - mean) * rstd * g[i * 64 + t] + bt[i * 64 + t];
    h[row * Dc + i * 64 + t] = o;
    hb[row * Dc + i * 64 + t] = f2bf(o);
  }
}

// ---------------------------------------------------------------------------
__global__ void gather_kernel(const float* __restrict__ h, float* __restrict__ y, int p0)
{
  const int pl = blockIdx.x >> 4;
  const int b  = blockIdx.x & 15;
  const int p  = p0 + pl;
  const float* src = h + ((size_t)((pl * Bc + b) * Tc + p)) * Dc;
  float* dst = y + ((size_t)(b * Tc + p)) * Dc;
  dst[threadIdx.x] = src[threadIdx.x];
}

__global__ __launch_bounds__(256) void cls_kernel(
    const float* __restrict__ y, const float* __restrict__ w1, const float* __restrict__ b1,
    const float* __restrict__ w2, const float* __restrict__ b2, float* __restrict__ out)
{
  const int row = blockIdx.x;
  const int j = threadIdx.x;
  __shared__ float ys[512];
  ys[j]       = y[(size_t)row * Dc + j];
  ys[j + 256] = y[(size_t)row * Dc + 256 + j];
  __syncthreads();

  float acc = b1[j];
  for (int d = 0; d < 512; ++d) acc += ys[d] * w1[(size_t)d * 256 + j];
  acc = fmaxf(acc, 0.f);

  float c0 = acc * w2[j * 2 + 0];
  float c1 = acc * w2[j * 2 + 1];
  c0 = wave_sum(c0);
  c1 = wave_sum(c1);

  __shared__ float r0[4], r1[4];
  const int w = j >> 6, lane = j & 63;
  if (lane == 0) { r0[w] = c0; r1[w] = c1; }
  __syncthreads();
  if (j == 0) {
    const float z0 = r0[0] + r0[1] + r0[2] + r0[3] + b2[0];
    const float z1 = r1[0] + r1[1] + r1[2] + r1[3] + b2[1];
    const float mz = fmaxf(z0, z1);
    const float lse = mz + logf(expf(z0 - mz) + expf(z1 - mz));
    out[row * 2 + 0] = z0 - lse;
    out[row * 2 + 1] = z1 - lse;
  }
}

// ---------------------------------------------------------------------------
extern "C" void kernel_launch(void* const* d_in, const int* in_sizes, int n_in,
                              void* d_out, int out_size, void* d_ws, size_t ws_size,
                              hipStream_t stream)
{
  if (n_in < 19) return;
  const float* x      = (const float*)d_in[0];
  const float* fc_w   = (const float*)d_in[1];
  const float* fc_b   = (const float*)d_in[2];
  const float* w_qkv  = (const float*)d_in[3];
  const float* b_qkv  = (const float*)d_in[4];
  const float* w_o    = (const float*)d_in[5];
  const float* b_o    = (const float*)d_in[6];
  const float* ln1_g  = (const float*)d_in[7];
  const float* ln1_b  = (const float*)d_in[8];
  const float* w_ff1  = (const float*)d_in[9];
  const float* b_ff1  = (const float*)d_in[10];
  const float* w_ff2  = (const float*)d_in[11];
  const float* b_ff2  = (const float*)d_in[12];
  const float* ln2_g  = (const float*)d_in[13];
  const float* ln2_b  = (const float*)d_in[14];
  const float* cls_w1 = (const float*)d_in[15];
  const float* cls_b1 = (const float*)d_in[16];
  const float* cls_w2 = (const float*)d_in[17];
  const float* cls_b2 = (const float*)d_in[18];
  float* out = (float*)d_out;

  // ---- workspace carve -----------------------------------------------------
  char* wp = (char*)d_ws;
  auto alloc = [&](size_t bytes) -> char* {
    char* p = wp; wp += (bytes + 255) & ~(size_t)255; return p;
  };
  float* h0 = (float*)alloc((size_t)Bc * Tc * Dc * 4);
  float* yb = (float*)alloc((size_t)Bc * Tc * Dc * 4);
  u16 *wtq[Lc], *wto[Lc], *wtf1[Lc], *wtf2[Lc];
  for (int l = 0; l < Lc; ++l) {
    wtq[l]  = (u16*)alloc((size_t)3 * Dc * Dc * 2);   // [1536][512]
    wto[l]  = (u16*)alloc((size_t)Dc * Dc * 2);       // [512][512]
    wtf1[l] = (u16*)alloc((size_t)Fc * Dc * 2);       // [2048][512]
    wtf2[l] = (u16*)alloc((size_t)Dc * Fc * 2);       // [512][2048]
  }
  const size_t fixed = (size_t)(wp - (char*)d_ws);
  const size_t per_row = 2048 + 1024 + 3072 + 1024 + 2048 + 4096;  // 13312 B
  int PC = 64;
  while (PC > 1 && fixed + (size_t)PC * 1024 * per_row + 4096 > ws_size) PC >>= 1;
  if (fixed + (size_t)PC * 1024 * per_row + 4096 > ws_size) return;
  const size_t R = (size_t)PC * Bc * Tc;

  float* h     = (float*)alloc(R * Dc * 4);
  u16*   hb    = (u16*)  alloc(R * Dc * 2);
  u16*   qkvb  = (u16*)  alloc(R * 3 * Dc * 2);
  u16*   attno = (u16*)  alloc(R * Dc * 2);
  float* tmp   = (float*)alloc(R * Dc * 4);
  u16*   ffb   = (u16*)  alloc(R * Fc * 2);

  // ---- weight transpose+convert (once per call) ----------------------------
  const dim3 tb(32, 8);
  for (int l = 0; l < Lc; ++l) {
    transpose_conv<<<dim3(3 * Dc / 32, Dc / 32), tb, 0, stream>>>(
        w_qkv + (size_t)l * Dc * 3 * Dc, wtq[l], Dc, 3 * Dc);
    transpose_conv<<<dim3(Dc / 32, Dc / 32), tb, 0, stream>>>(
        w_o + (size_t)l * Dc * Dc, wto[l], Dc, Dc);
    transpose_conv<<<dim3(Fc / 32, Dc / 32), tb, 0, stream>>>(
        w_ff1 + (size_t)l * Dc * Fc, wtf1[l], Dc, Fc);
    transpose_conv<<<dim3(Dc / 32, Fc / 32), tb, 0, stream>>>(
        w_ff2 + (size_t)l * Fc * Dc, wtf2[l], Fc, Dc);
  }

  // ---- fc: h0 = relu(x @ fc_w + fc_b) --------------------------------------
  gemm_kernel<true><<<dim3(Dc / 64, (Bc * Tc) / 128), 256, 0, stream>>>(
      x, fc_w, fc_b, h0, Bc * Tc, INc, Dc);

  for (int p0 = 0; p0 < Tc; p0 += PC) {
    const int n4 = (int)(R * Dc / 4);
    bcast_kernel<<<(n4 + 255) / 256, 256, 0, stream>>>(
        (const float4*)h0, (float4*)h, (uint2*)hb, n4);

    for (int l = 0; l < Lc; ++l) {
      // qkv = hb @ Wqkv + b   (bf16 out)
      gemm_mfma<false, true><<<dim3(3 * Dc / 128, (int)(R / 128)), 256, 0, stream>>>(
          hb, wtq[l], b_qkv + (size_t)l * 3 * Dc, qkvb, (int)R, Dc, 3 * Dc);
      attn_kernel<<<dim3(Hc, Bc, PC), 64, 0, stream>>>(qkvb, attno, p0);
      // tmp = attno @ Wo + b_o  (fp32 out)
      gemm_mfma<false, false><<<dim3(Dc / 128, (int)(R / 128)), 256, 0, stream>>>(
          attno, wto[l], b_o + (size_t)l * Dc, tmp, (int)R, Dc, Dc);
      res_ln_kernel<<<(int)R, 64, 0, stream>>>(h, hb, tmp, ln1_g + l * Dc, ln1_b + l * Dc);
      // ff = relu(hb @ Wf1 + b)  (bf16 out)
      gemm_mfma<true, true><<<dim3(Fc / 128, (int)(R / 128)), 256, 0, stream>>>(
          hb, wtf1[l], b_ff1 + (size_t)l * Fc, ffb, (int)R, Dc, Fc);
      // tmp = ff @ Wf2 + b  (fp32 out)
      gemm_mfma<false, false><<<dim3(Dc / 128, (int)(R / 128)), 256, 0, stream>>>(
          ffb, wtf2[l], b_ff2 + (size_t)l * Dc, tmp, (int)R, Fc, Dc);
      res_ln_kernel<<<(int)R, 64, 0, stream>>>(h, hb, tmp, ln2_g + l * Dc, ln2_b + l * Dc);
    }
    gather_kernel<<<PC * Bc, Dc, 0, stream>>>(h, yb, p0);
  }

  cls_kernel<<<Bc * Tc, 256, 0, stream>>>(yb, cls_w1, cls_b1, cls_w2, cls_b2, out);
}

// Round 4
// 3163.263 us; speedup vs baseline: 8.7223x; 1.6504x over previous
//
#include <hip/hip_runtime.h>
#include <math.h>

using u16 = unsigned short;
using u32 = unsigned int;

constexpr int Bc = 16;     // batch
constexpr int Tc = 64;     // tokens == prefixes
constexpr int INc = 128;
constexpr int Dc = 512;
constexpr int Hc = 8;
constexpr int Fc = 2048;
constexpr int Lc = 4;
constexpr float SCALEc = 0.125f;  // 1/sqrt(64)

// Prefix groups (compacted triangular layout, chunked to fit workspace).
// rows(p) = 16*(p+1); cumulative through p = 8*(p+1)*(p+2).
constexpr int NGc = 4;
constexpr int g_p0[NGc]   = {0, 32, 45, 55};
constexpr int g_np[NGc]   = {32, 13, 10, 9};
constexpr int g_start[NGc]= {0, 8448, 16560, 24640};     // global row start
constexpr int g_M[NGc]    = {8448, 8192, 8192, 8704};    // padded rows (%128==0)
constexpr int GMAXc = 8704;

typedef __attribute__((ext_vector_type(8))) short bf16x8;
typedef __attribute__((ext_vector_type(4))) float f32x4;

__device__ __forceinline__ float bf2f(u16 u) {
  union { u32 i; float f; } c; c.i = (u32)u << 16; return c.f;
}
__device__ __forceinline__ u16 f2bf(float f) {
  union { float f; u32 u; } c{f};
  u32 r = (c.u + 0x7fffu + ((c.u >> 16) & 1u)) >> 16;
  return (u16)r;
}

// ---------------------------------------------------------------------------
// fp32 GEMM (kept only for the small fc layer: M=1024,K=128,N=512)
// ---------------------------------------------------------------------------
template<bool RELU>
__global__ __launch_bounds__(256) void gemm_kernel(
    const float* __restrict__ A, const float* __restrict__ W,
    const float* __restrict__ bias, float* __restrict__ C,
    int M, int K, int N)
{
  __shared__ float As[128][17];
  __shared__ float Ws[16][64];
  const int tid = threadIdx.x;
  const int tx = tid & 15, ty = tid >> 4;
  const int row0 = blockIdx.y * 128, col0 = blockIdx.x * 64;
  float acc[8][4];
#pragma unroll
  for (int i = 0; i < 8; ++i)
#pragma unroll
    for (int j = 0; j < 4; ++j) acc[i][j] = 0.f;
  const int ar = tid >> 1, ak = (tid & 1) * 8;
  const int wr = tid >> 4, wc = (tid & 15) * 4;
  for (int k0 = 0; k0 < K; k0 += 16) {
    const float* ap = A + (size_t)(row0 + ar) * K + k0 + ak;
    float4 a0 = *(const float4*)ap;
    float4 a1 = *(const float4*)(ap + 4);
    As[ar][ak+0]=a0.x; As[ar][ak+1]=a0.y; As[ar][ak+2]=a0.z; As[ar][ak+3]=a0.w;
    As[ar][ak+4]=a1.x; As[ar][ak+5]=a1.y; As[ar][ak+6]=a1.z; As[ar][ak+7]=a1.w;
    *(float4*)&Ws[wr][wc] = *(const float4*)(W + (size_t)(k0 + wr) * N + col0 + wc);
    __syncthreads();
#pragma unroll
    for (int kk = 0; kk < 16; ++kk) {
      const float4 w4 = *(const float4*)&Ws[kk][tx * 4];
#pragma unroll
      for (int i = 0; i < 8; ++i) {
        const float av = As[ty + 16 * i][kk];
        acc[i][0] += av * w4.x; acc[i][1] += av * w4.y;
        acc[i][2] += av * w4.z; acc[i][3] += av * w4.w;
      }
    }
    __syncthreads();
  }
#pragma unroll
  for (int i = 0; i < 8; ++i) {
    const int r = row0 + ty + 16 * i, c = col0 + tx * 4;
    float4 v;
    v.x = acc[i][0] + bias[c+0]; v.y = acc[i][1] + bias[c+1];
    v.z = acc[i][2] + bias[c+2]; v.w = acc[i][3] + bias[c+3];
    if (RELU) { v.x=fmaxf(v.x,0.f); v.y=fmaxf(v.y,0.f); v.z=fmaxf(v.z,0.f); v.w=fmaxf(v.w,0.f); }
    *(float4*)&C[(size_t)r * N + c] = v;
  }
}

// ---------------------------------------------------------------------------
// Weight convert+transpose: src fp32 [K][N] -> dst bf16 [N][K]
// ---------------------------------------------------------------------------
__global__ __launch_bounds__(256) void transpose_conv(
    const float* __restrict__ src, u16* __restrict__ dst, int K, int N)
{
  __shared__ float t[32][33];
  const int bx = blockIdx.x * 32;   // n
  const int by = blockIdx.y * 32;   // k
  const int x = threadIdx.x, y = threadIdx.y;  // 32 x 8
#pragma unroll
  for (int i = 0; i < 32; i += 8) t[y + i][x] = src[(size_t)(by + y + i) * N + bx + x];
  __syncthreads();
#pragma unroll
  for (int i = 0; i < 32; i += 8)
    dst[(size_t)(bx + y + i) * K + by + x] = f2bf(t[x][y + i]);
}

// ---------------------------------------------------------------------------
// bf16 MFMA GEMM: C[M,N] = op(A[M,K] @ Wt[N,K]^T + bias), 128x128 tile, BK=64.
// ---------------------------------------------------------------------------
__device__ __forceinline__ void stage_tile(const u16* __restrict__ src, int ldk, u16* lds)
{
  const int tid = threadIdx.x;
#pragma unroll
  for (int q = 0; q < 4; ++q) {
    const int p16 = tid + (q << 8);      // 16B granule 0..1023
    const int row = p16 >> 3;            // 8 granules per 128B row
    const int s   = p16 & 7;
    const int k16 = s ^ (row & 7);       // pre-swizzled SOURCE, linear dest
    const u16* g = src + (size_t)row * ldk + (k16 << 3);
    __builtin_amdgcn_global_load_lds(
        (const __attribute__((address_space(1))) void*)g,
        (__attribute__((address_space(3))) void*)(lds + (p16 << 3)),
        16, 0, 0);
  }
}

template<bool RELU, bool OUT_BF16>
__global__ __launch_bounds__(256) void gemm_mfma(
    const u16* __restrict__ A,    // [M][K] bf16
    const u16* __restrict__ Wt,   // [N][K] bf16
    const float* __restrict__ bias,
    void* __restrict__ Cout,
    int M, int K, int N)
{
  __shared__ u16 As[2][128 * 64];
  __shared__ u16 Bs[2][128 * 64];

  const int tid  = threadIdx.x;
  const int lane = tid & 63;
  const int wave = tid >> 6;
  const int wr = wave >> 1;
  const int wc = wave & 1;
  const int row0 = blockIdx.y * 128;
  const int col0 = blockIdx.x * 128;

  f32x4 acc[4][4];
#pragma unroll
  for (int i = 0; i < 4; ++i)
#pragma unroll
    for (int j = 0; j < 4; ++j) acc[i][j] = f32x4{0.f, 0.f, 0.f, 0.f};

  const int nk = K >> 6;
  stage_tile(A  + (size_t)row0 * K, K, &As[0][0]);
  stage_tile(Wt + (size_t)col0 * K, K, &Bs[0][0]);
  asm volatile("s_waitcnt vmcnt(0)" ::: "memory");
  __syncthreads();

  const int arow = wr * 64 + (lane & 15);
  const int brow = wc * 64 + (lane & 15);
  const int kq   = lane >> 4;

  for (int t = 0; t < nk; ++t) {
    const int cur = t & 1;
    if (t + 1 < nk) {
      const int k0 = (t + 1) << 6;
      stage_tile(A  + (size_t)row0 * K + k0, K, &As[cur ^ 1][0]);
      stage_tile(Wt + (size_t)col0 * K + k0, K, &Bs[cur ^ 1][0]);
    }
    const u16* Ab = &As[cur][0];
    const u16* Bb = &Bs[cur][0];
#pragma unroll
    for (int kk = 0; kk < 2; ++kk) {
      bf16x8 af[4], bfr[4];
      const int c = kk * 4 + kq;
#pragma unroll
      for (int i = 0; i < 4; ++i) {
        const int ra = arow + i * 16;
        af[i]  = *reinterpret_cast<const bf16x8*>(Ab + ra * 64 + ((c ^ (ra & 7)) << 3));
        const int rb = brow + i * 16;
        bfr[i] = *reinterpret_cast<const bf16x8*>(Bb + rb * 64 + ((c ^ (rb & 7)) << 3));
      }
#pragma unroll
      for (int mi = 0; mi < 4; ++mi)
#pragma unroll
        for (int ni = 0; ni < 4; ++ni)
          acc[mi][ni] = __builtin_amdgcn_mfma_f32_16x16x32_bf16(af[mi], bfr[ni], acc[mi][ni], 0, 0, 0);
    }
    asm volatile("s_waitcnt vmcnt(0)" ::: "memory");
    __syncthreads();
  }

  const int r0 = row0 + wr * 64 + ((lane >> 4) << 2);
  const int c0 = col0 + wc * 64 + (lane & 15);
#pragma unroll
  for (int mi = 0; mi < 4; ++mi)
#pragma unroll
    for (int ni = 0; ni < 4; ++ni) {
      const int col = c0 + ni * 16;
      const float bsv = bias[col];
#pragma unroll
      for (int j = 0; j < 4; ++j) {
        const int row = r0 + mi * 16 + j;
        float o = acc[mi][ni][j] + bsv;
        if (RELU) o = fmaxf(o, 0.f);
        if (OUT_BF16) ((u16*)Cout)[(size_t)row * N + col] = f2bf(o);
        else          ((float*)Cout)[(size_t)row * N + col] = o;
      }
    }
}

// ---------------------------------------------------------------------------
// Broadcast h0 into group-local compacted layout.
// local row(p,b,t) = (p+1)(8p+b) + t - gstart, t <= p. grid (t, b, p-local).
// ---------------------------------------------------------------------------
__global__ __launch_bounds__(128) void bcast_kernel(
    const float* __restrict__ h0, float* __restrict__ h, u16* __restrict__ hb,
    int p0, int gstart)
{
  const int t = blockIdx.x, b = blockIdx.y, p = p0 + blockIdx.z;
  if (t > p) return;
  const size_t row = (size_t)(p + 1) * (8 * p + b) + t - gstart;
  const float4 v = ((const float4*)(h0 + ((size_t)(b * 64 + t)) * Dc))[threadIdx.x];
  ((float4*)(h + row * Dc))[threadIdx.x] = v;
  uint2 pk;
  pk.x = (u32)f2bf(v.x) | ((u32)f2bf(v.y) << 16);
  pk.y = (u32)f2bf(v.z) | ((u32)f2bf(v.w) << 16);
  ((uint2*)(hb + row * Dc))[threadIdx.x] = pk;
}

// ---------------------------------------------------------------------------
// Flash attention, group-local compacted layout. One 64-thread block per
// (head, b, p). K/V staged via global_load_lds; chunked online-softmax in
// registers (all indices static). Thread = query row.
// ---------------------------------------------------------------------------
__global__ __launch_bounds__(64) void attn_kernel(
    const u16* __restrict__ qkv, u16* __restrict__ attno,
    int p0, int gstart, int Mg)
{
  const int hh = blockIdx.x, b = blockIdx.y, p = p0 + blockIdx.z;
  const int NT = p + 1;
  const int rb = NT * (8 * p + b) - gstart;   // local row base
  const int tid = threadIdx.x;

  __shared__ u16 Ks[64][64];
  __shared__ u16 Vs[64][64];

  const int lrow = tid >> 3;            // 0..7
  const int lc16 = (tid & 7) * 8;       // u16 offset of 16B chunk
  for (int t0 = 0; t0 < NT; t0 += 8) {
    int tr = rb + t0 + lrow;
    if (tr >= Mg) tr = Mg - 1;          // stay in buffer (rows never consumed)
    const u16* gk = qkv + (size_t)tr * 1536 + 512 + hh * 64 + lc16;
    const u16* gv = qkv + (size_t)tr * 1536 + 1024 + hh * 64 + lc16;
    __builtin_amdgcn_global_load_lds(
        (const __attribute__((address_space(1))) void*)gk,
        (__attribute__((address_space(3))) void*)(&Ks[t0][0] + tid * 8), 16, 0, 0);
    __builtin_amdgcn_global_load_lds(
        (const __attribute__((address_space(1))) void*)gv,
        (__attribute__((address_space(3))) void*)(&Vs[t0][0] + tid * 8), 16, 0, 0);
  }

  // own query row -> f32 registers
  int qr = rb + ((tid < NT) ? tid : 0);
  const u16* qp = qkv + (size_t)qr * 1536 + hh * 64;
  float qv[64];
#pragma unroll
  for (int c8 = 0; c8 < 8; ++c8) {
    const bf16x8 q8 = *reinterpret_cast<const bf16x8*>(qp + c8 * 8);
#pragma unroll
    for (int i = 0; i < 8; ++i) qv[c8 * 8 + i] = bf2f((u16)q8[i]);
  }
  asm volatile("s_waitcnt vmcnt(0)" ::: "memory");
  __syncthreads();

  float o[64];
#pragma unroll
  for (int d = 0; d < 64; ++d) o[d] = 0.f;
  float m = -1e30f, sum = 0.f;

  for (int k0 = 0; k0 < NT; k0 += 8) {
    const int kn = (NT - k0 < 8) ? (NT - k0) : 8;   // wave-uniform
    float dots[8];
#pragma unroll
    for (int kk = 0; kk < 8; ++kk) {
      float dot = -1e30f;
      if (kk < kn) {
        dot = 0.f;
#pragma unroll
        for (int c8 = 0; c8 < 8; ++c8) {
          const bf16x8 k8 = *reinterpret_cast<const bf16x8*>(&Ks[k0 + kk][c8 * 8]);
#pragma unroll
          for (int i = 0; i < 8; ++i) dot += qv[c8 * 8 + i] * bf2f((u16)k8[i]);
        }
        dot *= SCALEc;
      }
      dots[kk] = dot;
    }
    float mc = dots[0];
#pragma unroll
    for (int kk = 1; kk < 8; ++kk) mc = fmaxf(mc, dots[kk]);
    const float mn = fmaxf(m, mc);
    const float scale = __expf(m - mn);  // first chunk: exp(-inf)=0
    float pk[8], psum = 0.f;
#pragma unroll
    for (int kk = 0; kk < 8; ++kk) { pk[kk] = __expf(dots[kk] - mn); psum += pk[kk]; }
    sum = sum * scale + psum;
    m = mn;
#pragma unroll
    for (int d = 0; d < 64; ++d) o[d] *= scale;
#pragma unroll
    for (int kk = 0; kk < 8; ++kk) {
      if (kk < kn) {
#pragma unroll
        for (int c8 = 0; c8 < 8; ++c8) {
          const bf16x8 v8 = *reinterpret_cast<const bf16x8*>(&Vs[k0 + kk][c8 * 8]);
#pragma unroll
          for (int i = 0; i < 8; ++i) o[c8 * 8 + i] += pk[kk] * bf2f((u16)v8[i]);
        }
      }
    }
  }

  if (tid < NT) {
    const float inv = 1.f / sum;
    u16* dst = attno + (size_t)(rb + tid) * Dc + hh * 64;
#pragma unroll
    for (int c8 = 0; c8 < 8; ++c8) {
      uint4 w;
      w.x = (u32)f2bf(o[c8*8+0]*inv) | ((u32)f2bf(o[c8*8+1]*inv) << 16);
      w.y = (u32)f2bf(o[c8*8+2]*inv) | ((u32)f2bf(o[c8*8+3]*inv) << 16);
      w.z = (u32)f2bf(o[c8*8+4]*inv) | ((u32)f2bf(o[c8*8+5]*inv) << 16);
      w.w = (u32)f2bf(o[c8*8+6]*inv) | ((u32)f2bf(o[c8*8+7]*inv) << 16);
      *reinterpret_cast<uint4*>(dst + c8 * 8) = w;
    }
  }
}

// ---------------------------------------------------------------------------
// h = LN(h + tmp); writes fp32 h and bf16 hb. 256 threads = 4 rows/block.
// ---------------------------------------------------------------------------
__device__ inline float wave_sum(float v) {
#pragma unroll
  for (int off = 32; off; off >>= 1) v += __shfl_xor(v, off);
  return v;
}

__global__ __launch_bounds__(256) void res_ln_kernel(
    float* __restrict__ h, u16* __restrict__ hb, const float* __restrict__ tmp,
    const float* __restrict__ g, const float* __restrict__ bt)
{
  const size_t row = (size_t)blockIdx.x * 4 + (threadIdx.x >> 6);
  const int t = threadIdx.x & 63;
  float v[8];
  float s = 0.f;
#pragma unroll
  for (int i = 0; i < 8; ++i) {
    v[i] = h[row * Dc + i * 64 + t] + tmp[row * Dc + i * 64 + t];
    s += v[i];
  }
  s = wave_sum(s);
  const float mean = s * (1.f / 512.f);
  float vs = 0.f;
#pragma unroll
  for (int i = 0; i < 8; ++i) { const float d = v[i] - mean; vs += d * d; }
  vs = wave_sum(vs);
  const float rstd = rsqrtf(vs * (1.f / 512.f) + 1e-5f);
#pragma unroll
  for (int i = 0; i < 8; ++i) {
    const float o = (v[i] - mean) * rstd * g[i * 64 + t] + bt[i * 64 + t];
    h[row * Dc + i * 64 + t] = o;
    hb[row * Dc + i * 64 + t] = f2bf(o);
  }
}

// ---------------------------------------------------------------------------
// y[(b,p),:] = h[local row(p,b,p),:]
// ---------------------------------------------------------------------------
__global__ void gather_kernel(const float* __restrict__ h, float* __restrict__ y,
                              int p0, int gstart)
{
  const int pl = blockIdx.x >> 4;
  const int b  = blockIdx.x & 15;
  const int p  = p0 + pl;
  const size_t row = (size_t)(p + 1) * (8 * p + b) + p - gstart;
  y[((size_t)(b * 64 + p)) * Dc + threadIdx.x] = h[row * Dc + threadIdx.x];
}

__global__ __launch_bounds__(256) void cls_kernel(
    const float* __restrict__ y, const float* __restrict__ w1, const float* __restrict__ b1,
    const float* __restrict__ w2, const float* __restrict__ b2, float* __restrict__ out)
{
  const int row = blockIdx.x;
  const int j = threadIdx.x;
  __shared__ float ys[512];
  ys[j]       = y[(size_t)row * Dc + j];
  ys[j + 256] = y[(size_t)row * Dc + 256 + j];
  __syncthreads();

  float acc = b1[j];
  for (int d = 0; d < 512; ++d) acc += ys[d] * w1[(size_t)d * 256 + j];
  acc = fmaxf(acc, 0.f);

  float c0 = acc * w2[j * 2 + 0];
  float c1 = acc * w2[j * 2 + 1];
  c0 = wave_sum(c0);
  c1 = wave_sum(c1);

  __shared__ float r0[4], r1[4];
  const int w = j >> 6, lane = j & 63;
  if (lane == 0) { r0[w] = c0; r1[w] = c1; }
  __syncthreads();
  if (j == 0) {
    const float z0 = r0[0] + r0[1] + r0[2] + r0[3] + b2[0];
    const float z1 = r1[0] + r1[1] + r1[2] + r1[3] + b2[1];
    const float mz = fmaxf(z0, z1);
    const float lse = mz + logf(expf(z0 - mz) + expf(z1 - mz));
    out[row * 2 + 0] = z0 - lse;
    out[row * 2 + 1] = z1 - lse;
  }
}

// ---------------------------------------------------------------------------
extern "C" void kernel_launch(void* const* d_in, const int* in_sizes, int n_in,
                              void* d_out, int out_size, void* d_ws, size_t ws_size,
                              hipStream_t stream)
{
  if (n_in < 19) return;
  const float* x      = (const float*)d_in[0];
  const float* fc_w   = (const float*)d_in[1];
  const float* fc_b   = (const float*)d_in[2];
  const float* w_qkv  = (const float*)d_in[3];
  const float* b_qkv  = (const float*)d_in[4];
  const float* w_o    = (const float*)d_in[5];
  const float* b_o    = (const float*)d_in[6];
  const float* ln1_g  = (const float*)d_in[7];
  const float* ln1_b  = (const float*)d_in[8];
  const float* w_ff1  = (const float*)d_in[9];
  const float* b_ff1  = (const float*)d_in[10];
  const float* w_ff2  = (const float*)d_in[11];
  const float* b_ff2  = (const float*)d_in[12];
  const float* ln2_g  = (const float*)d_in[13];
  const float* ln2_b  = (const float*)d_in[14];
  const float* cls_w1 = (const float*)d_in[15];
  const float* cls_b1 = (const float*)d_in[16];
  const float* cls_w2 = (const float*)d_in[17];
  const float* cls_b2 = (const float*)d_in[18];
  float* out = (float*)d_out;

  // ---- workspace carve (~146 MB total) --------------------------------------
  char* wp = (char*)d_ws;
  auto alloc = [&](size_t bytes) -> char* {
    char* p = wp; wp += (bytes + 255) & ~(size_t)255; return p;
  };
  float* h0 = (float*)alloc((size_t)Bc * Tc * Dc * 4);
  float* yb = (float*)alloc((size_t)Bc * Tc * Dc * 4);
  u16 *wtq[Lc], *wto[Lc], *wtf1[Lc], *wtf2[Lc];
  for (int l = 0; l < Lc; ++l) {
    wtq[l]  = (u16*)alloc((size_t)3 * Dc * Dc * 2);
    wto[l]  = (u16*)alloc((size_t)Dc * Dc * 2);
    wtf1[l] = (u16*)alloc((size_t)Fc * Dc * 2);
    wtf2[l] = (u16*)alloc((size_t)Dc * Fc * 2);
  }
  float* h     = (float*)alloc((size_t)GMAXc * Dc * 4);
  u16*   hb    = (u16*)  alloc((size_t)GMAXc * Dc * 2);
  u16*   qkvb  = (u16*)  alloc((size_t)GMAXc * 3 * Dc * 2);
  u16*   attno = (u16*)  alloc((size_t)GMAXc * Dc * 2);
  float* tmp   = (float*)alloc((size_t)GMAXc * Dc * 4);
  u16*   ffb   = (u16*)  alloc((size_t)GMAXc * Fc * 2);
  if ((size_t)(wp - (char*)d_ws) > ws_size) return;

  // ---- weight transpose+convert (once per call) ----------------------------
  const dim3 tb(32, 8);
  for (int l = 0; l < Lc; ++l) {
    transpose_conv<<<dim3(3 * Dc / 32, Dc / 32), tb, 0, stream>>>(
        w_qkv + (size_t)l * Dc * 3 * Dc, wtq[l], Dc, 3 * Dc);
    transpose_conv<<<dim3(Dc / 32, Dc / 32), tb, 0, stream>>>(
        w_o + (size_t)l * Dc * Dc, wto[l], Dc, Dc);
    transpose_conv<<<dim3(Fc / 32, Dc / 32), tb, 0, stream>>>(
        w_ff1 + (size_t)l * Dc * Fc, wtf1[l], Dc, Fc);
    transpose_conv<<<dim3(Dc / 32, Fc / 32), tb, 0, stream>>>(
        w_ff2 + (size_t)l * Fc * Dc, wtf2[l], Fc, Dc);
  }

  // ---- fc: h0 = relu(x @ fc_w + fc_b) --------------------------------------
  gemm_kernel<true><<<dim3(Dc / 64, (Bc * Tc) / 128), 256, 0, stream>>>(
      x, fc_w, fc_b, h0, Bc * Tc, INc, Dc);

  for (int g = 0; g < NGc; ++g) {
    const int p0 = g_p0[g], np = g_np[g], gs = g_start[g], Mg = g_M[g];

    bcast_kernel<<<dim3(64, 16, np), 128, 0, stream>>>(h0, h, hb, p0, gs);

    for (int l = 0; l < Lc; ++l) {
      gemm_mfma<false, true><<<dim3(3 * Dc / 128, Mg / 128), 256, 0, stream>>>(
          hb, wtq[l], b_qkv + (size_t)l * 3 * Dc, qkvb, Mg, Dc, 3 * Dc);
      attn_kernel<<<dim3(Hc, Bc, np), 64, 0, stream>>>(qkvb, attno, p0, gs, Mg);
      gemm_mfma<false, false><<<dim3(Dc / 128, Mg / 128), 256, 0, stream>>>(
          attno, wto[l], b_o + (size_t)l * Dc, tmp, Mg, Dc, Dc);
      res_ln_kernel<<<Mg / 4, 256, 0, stream>>>(h, hb, tmp, ln1_g + l * Dc, ln1_b + l * Dc);
      gemm_mfma<true, true><<<dim3(Fc / 128, Mg / 128), 256, 0, stream>>>(
          hb, wtf1[l], b_ff1 + (size_t)l * Fc, ffb, Mg, Dc, Fc);
      gemm_mfma<false, false><<<dim3(Dc / 128, Mg / 128), 256, 0, stream>>>(
          ffb, wtf2[l], b_ff2 + (size_t)l * Dc, tmp, Mg, Fc, Dc);
      res_ln_kernel<<<Mg / 4, 256, 0, stream>>>(h, hb, tmp, ln2_g + l * Dc, ln2_b + l * Dc);
    }
    gather_kernel<<<np * Bc, Dc, 0, stream>>>(h, yb, p0, gs);
  }

  cls_kernel<<<Bc * Tc, 256, 0, stream>>>(yb, cls_w1, cls_b1, cls_w2, cls_b2, out);
}

// Round 5
// 2691.105 us; speedup vs baseline: 10.2526x; 1.1755x over previous
//
#include <hip/hip_runtime.h>
#include <math.h>

using u16 = unsigned short;
using u32 = unsigned int;

constexpr int Bc = 16;     // batch
constexpr int Tc = 64;     // tokens == prefixes
constexpr int INc = 128;
constexpr int Dc = 512;
constexpr int Hc = 8;
constexpr int Fc = 2048;
constexpr int Lc = 4;
constexpr float SCALEc = 0.125f;  // 1/sqrt(64)

// Prefix groups (compacted triangular layout, chunked to fit workspace).
constexpr int NGc = 4;
constexpr int g_p0[NGc]   = {0, 32, 45, 55};
constexpr int g_np[NGc]   = {32, 13, 10, 9};
constexpr int g_start[NGc]= {0, 8448, 16560, 24640};     // global row start
constexpr int g_M[NGc]    = {8448, 8192, 8192, 8704};    // padded rows (%128==0)
constexpr int g_M3[NGc]   = {512, 256, 256, 256};        // padded diag rows
constexpr int GMAXc = 8704;

typedef __attribute__((ext_vector_type(8))) short bf16x8;
typedef __attribute__((ext_vector_type(4))) float f32x4;

__device__ __forceinline__ float bf2f(u16 u) {
  union { u32 i; float f; } c; c.i = (u32)u << 16; return c.f;
}
__device__ __forceinline__ u16 f2bf(float f) {
  union { float f; u32 u; } c{f};
  u32 r = (c.u + 0x7fffu + ((c.u >> 16) & 1u)) >> 16;
  return (u16)r;
}

// ---------------------------------------------------------------------------
// fp32 GEMM (kept only for the small fc layer: M=1024,K=128,N=512)
// ---------------------------------------------------------------------------
template<bool RELU>
__global__ __launch_bounds__(256) void gemm_kernel(
    const float* __restrict__ A, const float* __restrict__ W,
    const float* __restrict__ bias, float* __restrict__ C,
    int M, int K, int N)
{
  __shared__ float As[128][17];
  __shared__ float Ws[16][64];
  const int tid = threadIdx.x;
  const int tx = tid & 15, ty = tid >> 4;
  const int row0 = blockIdx.y * 128, col0 = blockIdx.x * 64;
  float acc[8][4];
#pragma unroll
  for (int i = 0; i < 8; ++i)
#pragma unroll
    for (int j = 0; j < 4; ++j) acc[i][j] = 0.f;
  const int ar = tid >> 1, ak = (tid & 1) * 8;
  const int wr = tid >> 4, wc = (tid & 15) * 4;
  for (int k0 = 0; k0 < K; k0 += 16) {
    const float* ap = A + (size_t)(row0 + ar) * K + k0 + ak;
    float4 a0 = *(const float4*)ap;
    float4 a1 = *(const float4*)(ap + 4);
    As[ar][ak+0]=a0.x; As[ar][ak+1]=a0.y; As[ar][ak+2]=a0.z; As[ar][ak+3]=a0.w;
    As[ar][ak+4]=a1.x; As[ar][ak+5]=a1.y; As[ar][ak+6]=a1.z; As[ar][ak+7]=a1.w;
    *(float4*)&Ws[wr][wc] = *(const float4*)(W + (size_t)(k0 + wr) * N + col0 + wc);
    __syncthreads();
#pragma unroll
    for (int kk = 0; kk < 16; ++kk) {
      const float4 w4 = *(const float4*)&Ws[kk][tx * 4];
#pragma unroll
      for (int i = 0; i < 8; ++i) {
        const float av = As[ty + 16 * i][kk];
        acc[i][0] += av * w4.x; acc[i][1] += av * w4.y;
        acc[i][2] += av * w4.z; acc[i][3] += av * w4.w;
      }
    }
    __syncthreads();
  }
#pragma unroll
  for (int i = 0; i < 8; ++i) {
    const int r = row0 + ty + 16 * i, c = col0 + tx * 4;
    float4 v;
    v.x = acc[i][0] + bias[c+0]; v.y = acc[i][1] + bias[c+1];
    v.z = acc[i][2] + bias[c+2]; v.w = acc[i][3] + bias[c+3];
    if (RELU) { v.x=fmaxf(v.x,0.f); v.y=fmaxf(v.y,0.f); v.z=fmaxf(v.z,0.f); v.w=fmaxf(v.w,0.f); }
    *(float4*)&C[(size_t)r * N + c] = v;
  }
}

// ---------------------------------------------------------------------------
// Weight convert+transpose: src fp32 [K][N] -> dst bf16 [N][K]
// ---------------------------------------------------------------------------
__global__ __launch_bounds__(256) void transpose_conv(
    const float* __restrict__ src, u16* __restrict__ dst, int K, int N)
{
  __shared__ float t[32][33];
  const int bx = blockIdx.x * 32;   // n
  const int by = blockIdx.y * 32;   // k
  const int x = threadIdx.x, y = threadIdx.y;  // 32 x 8
#pragma unroll
  for (int i = 0; i < 32; i += 8) t[y + i][x] = src[(size_t)(by + y + i) * N + bx + x];
  __syncthreads();
#pragma unroll
  for (int i = 0; i < 32; i += 8)
    dst[(size_t)(bx + y + i) * K + by + x] = f2bf(t[x][y + i]);
}

// ---------------------------------------------------------------------------
// bf16 MFMA GEMM: C[M,N] = op(A[M,K] @ Wt[N,K]^T + bias), 128x128 tile, BK=64.
// ---------------------------------------------------------------------------
__device__ __forceinline__ void stage_tile(const u16* __restrict__ src, int ldk, u16* lds)
{
  const int tid = threadIdx.x;
#pragma unroll
  for (int q = 0; q < 4; ++q) {
    const int p16 = tid + (q << 8);      // 16B granule 0..1023
    const int row = p16 >> 3;            // 8 granules per 128B row
    const int s   = p16 & 7;
    const int k16 = s ^ (row & 7);       // pre-swizzled SOURCE, linear dest
    const u16* g = src + (size_t)row * ldk + (k16 << 3);
    __builtin_amdgcn_global_load_lds(
        (const __attribute__((address_space(1))) void*)g,
        (__attribute__((address_space(3))) void*)(lds + (p16 << 3)),
        16, 0, 0);
  }
}

template<bool RELU, bool OUT_BF16>
__global__ __launch_bounds__(256) void gemm_mfma(
    const u16* __restrict__ A,    // [M][K] bf16
    const u16* __restrict__ Wt,   // [N][K] bf16
    const float* __restrict__ bias,
    void* __restrict__ Cout,
    int M, int K, int N)
{
  __shared__ u16 As[2][128 * 64];
  __shared__ u16 Bs[2][128 * 64];

  const int tid  = threadIdx.x;
  const int lane = tid & 63;
  const int wave = tid >> 6;
  const int wr = wave >> 1;
  const int wc = wave & 1;
  const int row0 = blockIdx.y * 128;
  const int col0 = blockIdx.x * 128;

  f32x4 acc[4][4];
#pragma unroll
  for (int i = 0; i < 4; ++i)
#pragma unroll
    for (int j = 0; j < 4; ++j) acc[i][j] = f32x4{0.f, 0.f, 0.f, 0.f};

  const int nk = K >> 6;
  stage_tile(A  + (size_t)row0 * K, K, &As[0][0]);
  stage_tile(Wt + (size_t)col0 * K, K, &Bs[0][0]);
  asm volatile("s_waitcnt vmcnt(0)" ::: "memory");
  __syncthreads();

  const int arow = wr * 64 + (lane & 15);
  const int brow = wc * 64 + (lane & 15);
  const int kq   = lane >> 4;

  for (int t = 0; t < nk; ++t) {
    const int cur = t & 1;
    if (t + 1 < nk) {
      const int k0 = (t + 1) << 6;
      stage_tile(A  + (size_t)row0 * K + k0, K, &As[cur ^ 1][0]);
      stage_tile(Wt + (size_t)col0 * K + k0, K, &Bs[cur ^ 1][0]);
    }
    const u16* Ab = &As[cur][0];
    const u16* Bb = &Bs[cur][0];
#pragma unroll
    for (int kk = 0; kk < 2; ++kk) {
      bf16x8 af[4], bfr[4];
      const int c = kk * 4 + kq;
#pragma unroll
      for (int i = 0; i < 4; ++i) {
        const int ra = arow + i * 16;
        af[i]  = *reinterpret_cast<const bf16x8*>(Ab + ra * 64 + ((c ^ (ra & 7)) << 3));
        const int rb = brow + i * 16;
        bfr[i] = *reinterpret_cast<const bf16x8*>(Bb + rb * 64 + ((c ^ (rb & 7)) << 3));
      }
#pragma unroll
      for (int mi = 0; mi < 4; ++mi)
#pragma unroll
        for (int ni = 0; ni < 4; ++ni)
          acc[mi][ni] = __builtin_amdgcn_mfma_f32_16x16x32_bf16(af[mi], bfr[ni], acc[mi][ni], 0, 0, 0);
    }
    asm volatile("s_waitcnt vmcnt(0)" ::: "memory");
    __syncthreads();
  }

  const int r0 = row0 + wr * 64 + ((lane >> 4) << 2);
  const int c0 = col0 + wc * 64 + (lane & 15);
#pragma unroll
  for (int mi = 0; mi < 4; ++mi)
#pragma unroll
    for (int ni = 0; ni < 4; ++ni) {
      const int col = c0 + ni * 16;
      const float bsv = bias[col];
#pragma unroll
      for (int j = 0; j < 4; ++j) {
        const int row = r0 + mi * 16 + j;
        float o = acc[mi][ni][j] + bsv;
        if (RELU) o = fmaxf(o, 0.f);
        if (OUT_BF16) ((u16*)Cout)[(size_t)row * N + col] = f2bf(o);
        else          ((float*)Cout)[(size_t)row * N + col] = o;
      }
    }
}

// ---------------------------------------------------------------------------
// Broadcast h0 into group-local compacted layout.
// ---------------------------------------------------------------------------
__global__ __launch_bounds__(128) void bcast_kernel(
    const float* __restrict__ h0, float* __restrict__ h, u16* __restrict__ hb,
    int p0, int gstart)
{
  const int t = blockIdx.x, b = blockIdx.y, p = p0 + blockIdx.z;
  if (t > p) return;
  const size_t row = (size_t)(p + 1) * (8 * p + b) + t - gstart;
  const float4 v = ((const float4*)(h0 + ((size_t)(b * 64 + t)) * Dc))[threadIdx.x];
  ((float4*)(h + row * Dc))[threadIdx.x] = v;
  uint2 pk;
  pk.x = (u32)f2bf(v.x) | ((u32)f2bf(v.y) << 16);
  pk.y = (u32)f2bf(v.z) | ((u32)f2bf(v.w) << 16);
  ((uint2*)(hb + row * Dc))[threadIdx.x] = pk;
}

// ---------------------------------------------------------------------------
// Flash attention v2 (layers 0..2). One 64-thread block per (head,b,p,qblock):
// lane = (q within 16-query block) + 16*ks; 4-way key-slice split with
// shfl_xor online-softmax merge. K/V staged bf16 with XOR-swizzled source
// (linear global_load_lds dest) so reads are bank-conflict-free.
// ---------------------------------------------------------------------------
__global__ __launch_bounds__(64) void attn_kernel(
    const u16* __restrict__ qkv, u16* __restrict__ attno,
    int p0, int gstart, int Mg)
{
  const int hh = blockIdx.x, b = blockIdx.y;
  const int pl = blockIdx.z >> 2, qb = blockIdx.z & 3;
  const int p = p0 + pl;
  const int NT = p + 1;
  if (qb * 16 >= NT) return;
  const int rb = NT * (8 * p + b) - gstart;
  const int tid = threadIdx.x;
  const int q  = qb * 16 + (tid & 15);
  const int ks = tid >> 4;

  __shared__ u16 Ks[64][64];
  __shared__ u16 Vs[64][64];

  const int lrow = tid >> 3;            // 0..7
  const int lc8  = tid & 7;             // 16B chunk within row
  for (int t0 = 0; t0 < NT; t0 += 8) {
    int tr = rb + t0 + lrow;
    if (tr >= Mg) tr = Mg - 1;          // stay in buffer (rows never consumed)
    const int csrc = (lc8 ^ lrow) << 3; // pre-swizzled source chunk
    const u16* gk = qkv + (size_t)tr * 1536 + 512  + hh * 64 + csrc;
    const u16* gv = qkv + (size_t)tr * 1536 + 1024 + hh * 64 + csrc;
    __builtin_amdgcn_global_load_lds(
        (const __attribute__((address_space(1))) void*)gk,
        (__attribute__((address_space(3))) void*)(&Ks[t0][0] + tid * 8), 16, 0, 0);
    __builtin_amdgcn_global_load_lds(
        (const __attribute__((address_space(1))) void*)gv,
        (__attribute__((address_space(3))) void*)(&Vs[t0][0] + tid * 8), 16, 0, 0);
  }

  // own query row -> f32 registers
  const int qrow = rb + ((q < NT) ? q : 0);
  const u16* qp = qkv + (size_t)qrow * 1536 + hh * 64;
  float qv[64];
#pragma unroll
  for (int c8 = 0; c8 < 8; ++c8) {
    const bf16x8 q8 = *reinterpret_cast<const bf16x8*>(qp + c8 * 8);
#pragma unroll
    for (int i = 0; i < 8; ++i) qv[c8 * 8 + i] = bf2f((u16)q8[i]);
  }
  asm volatile("s_waitcnt vmcnt(0)" ::: "memory");
  __syncthreads();

  float o[64];
#pragma unroll
  for (int d = 0; d < 64; ++d) o[d] = 0.f;
  float m = -1e30f, sum = 0.f;

  const int njs = (NT + 3) >> 2;        // per-thread key steps
  for (int j0 = 0; j0 < njs; j0 += 4) {
    float dots[4];
#pragma unroll
    for (int jj = 0; jj < 4; ++jj) {
      const int k = (j0 + jj) * 4 + ks;
      float dot = -1e30f;
      if (k < NT) {
        dot = 0.f;
#pragma unroll
        for (int c8 = 0; c8 < 8; ++c8) {
          const bf16x8 k8 = *reinterpret_cast<const bf16x8*>(
              &Ks[k][0] + ((c8 ^ (k & 7)) << 3));
#pragma unroll
          for (int i = 0; i < 8; ++i) dot += qv[c8 * 8 + i] * bf2f((u16)k8[i]);
        }
        dot *= SCALEc;
      }
      dots[jj] = dot;
    }
    float mc = fmaxf(fmaxf(dots[0], dots[1]), fmaxf(dots[2], dots[3]));
    const float mn = fmaxf(m, mc);
    const float scale = __expf(m - mn);
    float pk[4], psum = 0.f;
#pragma unroll
    for (int jj = 0; jj < 4; ++jj) { pk[jj] = __expf(dots[jj] - mn); psum += pk[jj]; }
    sum = sum * scale + psum;
    m = mn;
#pragma unroll
    for (int d = 0; d < 64; ++d) o[d] *= scale;
#pragma unroll
    for (int jj = 0; jj < 4; ++jj) {
      const int k = (j0 + jj) * 4 + ks;
      if (k < NT) {
#pragma unroll
        for (int c8 = 0; c8 < 8; ++c8) {
          const bf16x8 v8 = *reinterpret_cast<const bf16x8*>(
              &Vs[k][0] + ((c8 ^ (k & 7)) << 3));
#pragma unroll
          for (int i = 0; i < 8; ++i) o[c8 * 8 + i] += pk[jj] * bf2f((u16)v8[i]);
        }
      }
    }
  }

  // merge the 4 key-slice partials (lanes differing in bits 4-5)
#pragma unroll
  for (int rnd = 0; rnd < 2; ++rnd) {
    const int off = 16 << rnd;
    const float mo = __shfl_xor(m, off);
    const float so = __shfl_xor(sum, off);
    const float mn = fmaxf(m, mo);
    const float fa = __expf(m - mn);
    const float fb = __expf(mo - mn);
#pragma unroll
    for (int d = 0; d < 64; ++d) {
      const float od = __shfl_xor(o[d], off);
      o[d] = o[d] * fa + od * fb;
    }
    sum = sum * fa + so * fb;
    m = mn;
  }

  if (ks == 0 && q < NT) {
    const float inv = 1.f / sum;
    u16* dst = attno + (size_t)(rb + q) * Dc + hh * 64;
#pragma unroll
    for (int c8 = 0; c8 < 8; ++c8) {
      uint4 w;
      w.x = (u32)f2bf(o[c8*8+0]*inv) | ((u32)f2bf(o[c8*8+1]*inv) << 16);
      w.y = (u32)f2bf(o[c8*8+2]*inv) | ((u32)f2bf(o[c8*8+3]*inv) << 16);
      w.z = (u32)f2bf(o[c8*8+4]*inv) | ((u32)f2bf(o[c8*8+5]*inv) << 16);
      w.w = (u32)f2bf(o[c8*8+6]*inv) | ((u32)f2bf(o[c8*8+7]*inv) << 16);
      *reinterpret_cast<uint4*>(dst + c8 * 8) = w;
    }
  }
}

// ---------------------------------------------------------------------------
// Layer-3 attention: only the diagonal query (token p). One 64-thread block
// per (head,b,p): thread = key; shfl softmax; shfl-broadcast PV (lane = d).
// Output row rd = pl*16 + b in the compact diag buffer.
// ---------------------------------------------------------------------------
__global__ __launch_bounds__(64) void attn_diag_kernel(
    const u16* __restrict__ qkv, u16* __restrict__ attno_d,
    int p0, int gstart, int Mg)
{
  const int hh = blockIdx.x, b = blockIdx.y, pl = blockIdx.z;
  const int p = p0 + pl;
  const int NT = p + 1;
  const int rb = NT * (8 * p + b) - gstart;
  const int tid = threadIdx.x;

  __shared__ u16 Ks[64][64];
  __shared__ u16 Vs[64][64];

  const int lrow = tid >> 3;
  const int lc8  = tid & 7;
  for (int t0 = 0; t0 < NT; t0 += 8) {
    int tr = rb + t0 + lrow;
    if (tr >= Mg) tr = Mg - 1;
    const int csrc = (lc8 ^ lrow) << 3;
    const u16* gk = qkv + (size_t)tr * 1536 + 512  + hh * 64 + csrc;
    const u16* gv = qkv + (size_t)tr * 1536 + 1024 + hh * 64 + csrc;
    __builtin_amdgcn_global_load_lds(
        (const __attribute__((address_space(1))) void*)gk,
        (__attribute__((address_space(3))) void*)(&Ks[t0][0] + tid * 8), 16, 0, 0);
    __builtin_amdgcn_global_load_lds(
        (const __attribute__((address_space(1))) void*)gv,
        (__attribute__((address_space(3))) void*)(&Vs[t0][0] + tid * 8), 16, 0, 0);
  }

  // the single query row (token p) -> registers (broadcast loads)
  const u16* qp = qkv + (size_t)(rb + NT - 1) * 1536 + hh * 64;
  float qv[64];
#pragma unroll
  for (int c8 = 0; c8 < 8; ++c8) {
    const bf16x8 q8 = *reinterpret_cast<const bf16x8*>(qp + c8 * 8);
#pragma unroll
    for (int i = 0; i < 8; ++i) qv[c8 * 8 + i] = bf2f((u16)q8[i]);
  }
  asm volatile("s_waitcnt vmcnt(0)" ::: "memory");
  __syncthreads();

  float dot = -1e30f;
  if (tid < NT) {
    dot = 0.f;
#pragma unroll
    for (int c8 = 0; c8 < 8; ++c8) {
      const bf16x8 k8 = *reinterpret_cast<const bf16x8*>(
          &Ks[tid][0] + ((c8 ^ (tid & 7)) << 3));
#pragma unroll
      for (int i = 0; i < 8; ++i) dot += qv[c8 * 8 + i] * bf2f((u16)k8[i]);
    }
    dot *= SCALEc;
  }
  float mm = dot;
#pragma unroll
  for (int off = 32; off; off >>= 1) mm = fmaxf(mm, __shfl_xor(mm, off));
  const float pt = __expf(dot - mm);    // invalid lanes -> 0
  float s = pt;
#pragma unroll
  for (int off = 32; off; off >>= 1) s += __shfl_xor(s, off);
  const float inv = 1.f / s;

  float o = 0.f;                        // lane owns output dim d = tid
  for (int t = 0; t < NT; ++t) {
    const float ptt = __shfl(pt, t);
    o += ptt * bf2f(Vs[t][(((tid >> 3) ^ (t & 7)) << 3) + (tid & 7)]);
  }
  const int rd = pl * 16 + b;
  attno_d[(size_t)rd * Dc + hh * 64 + tid] = f2bf(o * inv);
}

// ---------------------------------------------------------------------------
// h = LN(h + tmp); writes fp32 h and bf16 hb. 256 threads = 4 rows/block.
// ---------------------------------------------------------------------------
__device__ inline float wave_sum(float v) {
#pragma unroll
  for (int off = 32; off; off >>= 1) v += __shfl_xor(v, off);
  return v;
}

__global__ __launch_bounds__(256) void res_ln_kernel(
    float* __restrict__ h, u16* __restrict__ hb, const float* __restrict__ tmp,
    const float* __restrict__ g, const float* __restrict__ bt)
{
  const size_t row = (size_t)blockIdx.x * 4 + (threadIdx.x >> 6);
  const int t = threadIdx.x & 63;
  float v[8];
  float s = 0.f;
#pragma unroll
  for (int i = 0; i < 8; ++i) {
    v[i] = h[row * Dc + i * 64 + t] + tmp[row * Dc + i * 64 + t];
    s += v[i];
  }
  s = wave_sum(s);
  const float mean = s * (1.f / 512.f);
  float vs = 0.f;
#pragma unroll
  for (int i = 0; i < 8; ++i) { const float d = v[i] - mean; vs += d * d; }
  vs = wave_sum(vs);
  const float rstd = rsqrtf(vs * (1.f / 512.f) + 1e-5f);
#pragma unroll
  for (int i = 0; i < 8; ++i) {
    const float o = (v[i] - mean) * rstd * g[i * 64 + t] + bt[i * 64 + t];
    h[row * Dc + i * 64 + t] = o;
    hb[row * Dc + i * 64 + t] = f2bf(o);
  }
}

// ---------------------------------------------------------------------------
// Diag gather/scatter
// ---------------------------------------------------------------------------
__global__ __launch_bounds__(128) void gather_diag(
    const float* __restrict__ h, float* __restrict__ hd, u16* __restrict__ hbd,
    int p0, int gstart)
{
  const int pl = blockIdx.x >> 4, b = blockIdx.x & 15;
  const int p = p0 + pl;
  const size_t src = (size_t)(p + 1) * (8 * p + b) + p - gstart;
  const float4 v = ((const float4*)(h + src * Dc))[threadIdx.x];
  ((float4*)(hd + (size_t)blockIdx.x * Dc))[threadIdx.x] = v;
  uint2 pk;
  pk.x = (u32)f2bf(v.x) | ((u32)f2bf(v.y) << 16);
  pk.y = (u32)f2bf(v.z) | ((u32)f2bf(v.w) << 16);
  ((uint2*)(hbd + (size_t)blockIdx.x * Dc))[threadIdx.x] = pk;
}

__global__ __launch_bounds__(128) void scatter_out(
    const float* __restrict__ hd, float* __restrict__ yb, int p0)
{
  const int pl = blockIdx.x >> 4, b = blockIdx.x & 15;
  const int p = p0 + pl;
  ((float4*)(yb + ((size_t)(b * 64 + p)) * Dc))[threadIdx.x] =
      ((const float4*)(hd + (size_t)blockIdx.x * Dc))[threadIdx.x];
}

// ---------------------------------------------------------------------------
__global__ __launch_bounds__(256) void cls_kernel(
    const float* __restrict__ y, const float* __restrict__ w1, const float* __restrict__ b1,
    const float* __restrict__ w2, const float* __restrict__ b2, float* __restrict__ out)
{
  const int row = blockIdx.x;
  const int j = threadIdx.x;
  __shared__ float ys[512];
  ys[j]       = y[(size_t)row * Dc + j];
  ys[j + 256] = y[(size_t)row * Dc + 256 + j];
  __syncthreads();

  float acc = b1[j];
  for (int d = 0; d < 512; ++d) acc += ys[d] * w1[(size_t)d * 256 + j];
  acc = fmaxf(acc, 0.f);

  float c0 = acc * w2[j * 2 + 0];
  float c1 = acc * w2[j * 2 + 1];
  c0 = wave_sum(c0);
  c1 = wave_sum(c1);

  __shared__ float r0[4], r1[4];
  const int w = j >> 6, lane = j & 63;
  if (lane == 0) { r0[w] = c0; r1[w] = c1; }
  __syncthreads();
  if (j == 0) {
    const float z0 = r0[0] + r0[1] + r0[2] + r0[3] + b2[0];
    const float z1 = r1[0] + r1[1] + r1[2] + r1[3] + b2[1];
    const float mz = fmaxf(z0, z1);
    const float lse = mz + logf(expf(z0 - mz) + expf(z1 - mz));
    out[row * 2 + 0] = z0 - lse;
    out[row * 2 + 1] = z1 - lse;
  }
}

// ---------------------------------------------------------------------------
extern "C" void kernel_launch(void* const* d_in, const int* in_sizes, int n_in,
                              void* d_out, int out_size, void* d_ws, size_t ws_size,
                              hipStream_t stream)
{
  if (n_in < 19) return;
  const float* x      = (const float*)d_in[0];
  const float* fc_w   = (const float*)d_in[1];
  const float* fc_b   = (const float*)d_in[2];
  const float* w_qkv  = (const float*)d_in[3];
  const float* b_qkv  = (const float*)d_in[4];
  const float* w_o    = (const float*)d_in[5];
  const float* b_o    = (const float*)d_in[6];
  const float* ln1_g  = (const float*)d_in[7];
  const float* ln1_b  = (const float*)d_in[8];
  const float* w_ff1  = (const float*)d_in[9];
  const float* b_ff1  = (const float*)d_in[10];
  const float* w_ff2  = (const float*)d_in[11];
  const float* b_ff2  = (const float*)d_in[12];
  const float* ln2_g  = (const float*)d_in[13];
  const float* ln2_b  = (const float*)d_in[14];
  const float* cls_w1 = (const float*)d_in[15];
  const float* cls_b1 = (const float*)d_in[16];
  const float* cls_w2 = (const float*)d_in[17];
  const float* cls_b2 = (const float*)d_in[18];
  float* out = (float*)d_out;

  // ---- workspace carve (~148 MB total) --------------------------------------
  char* wp = (char*)d_ws;
  auto alloc = [&](size_t bytes) -> char* {
    char* p = wp; wp += (bytes + 255) & ~(size_t)255; return p;
  };
  float* h0 = (float*)alloc((size_t)Bc * Tc * Dc * 4);
  float* yb = (float*)alloc((size_t)Bc * Tc * Dc * 4);
  u16 *wtq[Lc], *wto[Lc], *wtf1[Lc], *wtf2[Lc];
  for (int l = 0; l < Lc; ++l) {
    wtq[l]  = (u16*)alloc((size_t)3 * Dc * Dc * 2);
    wto[l]  = (u16*)alloc((size_t)Dc * Dc * 2);
    wtf1[l] = (u16*)alloc((size_t)Fc * Dc * 2);
    wtf2[l] = (u16*)alloc((size_t)Dc * Fc * 2);
  }
  float* h     = (float*)alloc((size_t)GMAXc * Dc * 4);
  u16*   hb    = (u16*)  alloc((size_t)GMAXc * Dc * 2);
  u16*   qkvb  = (u16*)  alloc((size_t)GMAXc * 3 * Dc * 2);
  u16*   attno = (u16*)  alloc((size_t)GMAXc * Dc * 2);
  float* tmp   = (float*)alloc((size_t)GMAXc * Dc * 4);
  u16*   ffb   = (u16*)  alloc((size_t)GMAXc * Fc * 2);
  float* hdiag = (float*)alloc((size_t)512 * Dc * 4);
  u16*   hbdiag= (u16*)  alloc((size_t)512 * Dc * 2);
  u16*   attnd = (u16*)  alloc((size_t)512 * Dc * 2);
  if ((size_t)(wp - (char*)d_ws) > ws_size) return;

  // ---- weight transpose+convert (once per call) ----------------------------
  const dim3 tb(32, 8);
  for (int l = 0; l < Lc; ++l) {
    transpose_conv<<<dim3(3 * Dc / 32, Dc / 32), tb, 0, stream>>>(
        w_qkv + (size_t)l * Dc * 3 * Dc, wtq[l], Dc, 3 * Dc);
    transpose_conv<<<dim3(Dc / 32, Dc / 32), tb, 0, stream>>>(
        w_o + (size_t)l * Dc * Dc, wto[l], Dc, Dc);
    transpose_conv<<<dim3(Fc / 32, Dc / 32), tb, 0, stream>>>(
        w_ff1 + (size_t)l * Dc * Fc, wtf1[l], Dc, Fc);
    transpose_conv<<<dim3(Dc / 32, Fc / 32), tb, 0, stream>>>(
        w_ff2 + (size_t)l * Fc * Dc, wtf2[l], Fc, Dc);
  }

  // ---- fc: h0 = relu(x @ fc_w + fc_b) --------------------------------------
  gemm_kernel<true><<<dim3(Dc / 64, (Bc * Tc) / 128), 256, 0, stream>>>(
      x, fc_w, fc_b, h0, Bc * Tc, INc, Dc);

  for (int g = 0; g < NGc; ++g) {
    const int p0 = g_p0[g], np = g_np[g], gs = g_start[g], Mg = g_M[g];
    const int M3 = g_M3[g];

    bcast_kernel<<<dim3(64, 16, np), 128, 0, stream>>>(h0, h, hb, p0, gs);

    for (int l = 0; l < 3; ++l) {
      gemm_mfma<false, true><<<dim3(3 * Dc / 128, Mg / 128), 256, 0, stream>>>(
          hb, wtq[l], b_qkv + (size_t)l * 3 * Dc, qkvb, Mg, Dc, 3 * Dc);
      attn_kernel<<<dim3(Hc, Bc, np * 4), 64, 0, stream>>>(qkvb, attno, p0, gs, Mg);
      gemm_mfma<false, false><<<dim3(Dc / 128, Mg / 128), 256, 0, stream>>>(
          attno, wto[l], b_o + (size_t)l * Dc, tmp, Mg, Dc, Dc);
      res_ln_kernel<<<Mg / 4, 256, 0, stream>>>(h, hb, tmp, ln1_g + l * Dc, ln1_b + l * Dc);
      gemm_mfma<true, true><<<dim3(Fc / 128, Mg / 128), 256, 0, stream>>>(
          hb, wtf1[l], b_ff1 + (size_t)l * Fc, ffb, Mg, Dc, Fc);
      gemm_mfma<false, false><<<dim3(Dc / 128, Mg / 128), 256, 0, stream>>>(
          ffb, wtf2[l], b_ff2 + (size_t)l * Dc, tmp, Mg, Fc, Dc);
      res_ln_kernel<<<Mg / 4, 256, 0, stream>>>(h, hb, tmp, ln2_g + l * Dc, ln2_b + l * Dc);
    }

    // ---- layer 3: only diagonal rows matter after attention ---------------
    {
      const int l = 3;
      gemm_mfma<false, true><<<dim3(3 * Dc / 128, Mg / 128), 256, 0, stream>>>(
          hb, wtq[l], b_qkv + (size_t)l * 3 * Dc, qkvb, Mg, Dc, 3 * Dc);
      gather_diag<<<np * 16, 128, 0, stream>>>(h, hdiag, hbdiag, p0, gs);
      attn_diag_kernel<<<dim3(Hc, Bc, np), 64, 0, stream>>>(qkvb, attnd, p0, gs, Mg);
      gemm_mfma<false, false><<<dim3(Dc / 128, M3 / 128), 256, 0, stream>>>(
          attnd, wto[l], b_o + (size_t)l * Dc, tmp, M3, Dc, Dc);
      res_ln_kernel<<<M3 / 4, 256, 0, stream>>>(hdiag, hbdiag, tmp, ln1_g + l * Dc, ln1_b + l * Dc);
      gemm_mfma<true, true><<<dim3(Fc / 128, M3 / 128), 256, 0, stream>>>(
          hbdiag, wtf1[l], b_ff1 + (size_t)l * Fc, ffb, M3, Dc, Fc);
      gemm_mfma<false, false><<<dim3(Dc / 128, M3 / 128), 256, 0, stream>>>(
          ffb, wtf2[l], b_ff2 + (size_t)l * Dc, tmp, M3, Fc, Dc);
      res_ln_kernel<<<M3 / 4, 256, 0, stream>>>(hdiag, hbdiag, tmp, ln2_g + l * Dc, ln2_b + l * Dc);
      scatter_out<<<np * 16, 128, 0, stream>>>(hdiag, yb, p0);
    }
  }

  cls_kernel<<<Bc * Tc, 256, 0, stream>>>(yb, cls_w1, cls_b1, cls_w2, cls_b2, out);
}